// Round 8
// baseline (1780.239 us; speedup 1.0000x reference)
//
#include <hip/hip_runtime.h>
#include <hip/hip_bf16.h>
#include <cstdint>

#define NTOK 8192
#define NEXP 8
#define HID  2048
#define INTR 5632
#define NT1  44     // INTR/128 n-tiles for gemm1
#define NT2  16     // HID/128  n-tiles for gemm2

// ws offsets (bytes)
#define TCNT_OFF    4096u
#define SLOT_OFF    65536u      // slotlist: 18432 ints
#define T2S_OFF     262144u     // tok2slot: 32768 ints
#define W2_OFF      393216u     // w2: 32768 floats
#define LISTS_OFF   524288u     // lists: 65536 ints
#define WL_OFF      786432u     // wlists: 65536 floats
#define WG_OFF      2097152u
#define WBYTES      184549376u
#define WU_OFF      (WG_OFF + WBYTES)
#define HF_OFF      (WU_OFF + WBYTES)
#define HFBYTES     207618048u  // 72 mtiles * 176 kt * 16 frags * 1024 B
#define XG_OFF      (HF_OFF + HFBYTES)   // xg (75.5MB) then reused as pout

typedef float f32x4  __attribute__((ext_vector_type(4)));
typedef short s16x8  __attribute__((ext_vector_type(8)));
typedef short s16x4  __attribute__((ext_vector_type(4)));

__device__ __forceinline__ short bfc(float f) {
  __hip_bfloat16 h = __float2bfloat16(f);
  return __builtin_bit_cast(short, h);
}
__device__ __forceinline__ float b2f(short s) {
  unsigned u = ((unsigned)(unsigned short)s) << 16;
  return __builtin_bit_cast(float, u);
}
__device__ __forceinline__ s16x8 pk8(float4 a, float4 b) {
  s16x8 v;
  v[0]=bfc(a.x); v[1]=bfc(a.y); v[2]=bfc(a.z); v[3]=bfc(a.w);
  v[4]=bfc(b.x); v[5]=bfc(b.y); v[6]=bfc(b.z); v[7]=bfc(b.w);
  return v;
}
__device__ __forceinline__ void gload16(const void* g, void* l) {
  __builtin_amdgcn_global_load_lds((const __attribute__((address_space(1))) void*)g,
                                   (__attribute__((address_space(3))) void*)l, 16, 0, 0);
}

#define DSR128(dst, addr, IMM) \
  asm volatile("ds_read_b128 %0, %1 offset:" IMM : "=v"(dst) : "v"(addr))
#define DSW128(addr, data, IMM) \
  asm volatile("ds_write_b128 %0, %1 offset:" IMM :: "v"(addr), "v"(data))
#define WAITLGKM(N) do { \
  asm volatile("s_waitcnt lgkmcnt(" #N ")" ::: "memory"); \
  __builtin_amdgcn_sched_barrier(0); } while (0)
#define WAITVM(N) do { \
  asm volatile("s_waitcnt vmcnt(" #N ")" ::: "memory"); \
  __builtin_amdgcn_sched_barrier(0); } while (0)

// 4 A-fragment loads global->VGPR (frag stride 1024B), async; completion via WAITVM
#define LOADA4(D0, D1, D2, D3, PTR) \
  asm volatile("global_load_dwordx4 %0, %4, off\n\t" \
               "global_load_dwordx4 %1, %4, off offset:1024\n\t" \
               "global_load_dwordx4 %2, %4, off offset:2048\n\t" \
               "global_load_dwordx4 %3, %4, off offset:3072" \
               : "=&v"(D0), "=&v"(D1), "=&v"(D2), "=&v"(D3) : "v"(PTR))
// B gate+up 16B chunks global->VGPR
#define LOADB2(DG, DU, PG, PU) \
  asm volatile("global_load_dwordx4 %0, %2, off\n\t" \
               "global_load_dwordx4 %1, %3, off" \
               : "=&v"(DG), "=&v"(DU) : "v"(PG), "v"(PU))

#define MFMA_BF16 __builtin_amdgcn_mfma_f32_16x16x32_bf16

// ---------------- prep: f32 weights -> bf16 MFMA B-fragment layout ----------------
__global__ __launch_bounds__(256, 4) void prep_kernel(
    const float* __restrict__ src, short* __restrict__ dst,
    int KT, int NP, int Nsrc) {
  __shared__ float tile[32 * 132];
  const int b = blockIdx.x;
  const int np = b % NP;
  const int kt = (b / NP) % KT;
  const int e  = b / (NP * KT);
  const int tid = threadIdx.x;
  const float* s = src + (size_t)e * KT * 32 * (size_t)Nsrc + (size_t)kt * 32 * Nsrc + np * 128;
#pragma unroll
  for (int i = 0; i < 4; i++) {
    const int idx = tid + i * 256;
    const int row = idx >> 5, c4 = idx & 31;
    float4 v = *(const float4*)(s + (size_t)row * Nsrc + c4 * 4);
    *(float4*)(tile + row * 132 + c4 * 4) = v;
  }
  __syncthreads();
  short* dbase = dst + ((size_t)(e * KT + kt) * (NP * 8) + np * 8) * 512;
#pragma unroll
  for (int i = 0; i < 2; i++) {
    const int c = tid + i * 256;
    const int lane = c & 63;
    const int nf = c >> 6;
    const int n = nf * 16 + (lane & 15);
    const int kb = (lane >> 4) * 8;
    s16x8 o;
#pragma unroll
    for (int j = 0; j < 8; j++) o[j] = bfc(tile[(kb + j) * 132 + n]);
    *(s16x8*)(dbase + (size_t)c * 8) = o;
  }
}

// ---------------- router ----------------
__global__ void router_kernel(const float* __restrict__ x, const float* __restrict__ wr,
                              int* __restrict__ cnt, int* __restrict__ lists,
                              float* __restrict__ wlists) {
  const int wave = threadIdx.x >> 6;
  const int lane = threadIdx.x & 63;
  const int t = blockIdx.x * 4 + wave;
  if (t >= NTOK) return;
  float acc[NEXP];
#pragma unroll
  for (int e = 0; e < NEXP; e++) acc[e] = 0.f;
  const float* xrow = x + (size_t)t * HID;
#pragma unroll
  for (int j = 0; j < HID / 256; j++) {
    const int k = j * 256 + lane * 4;
    float4 xv = *(const float4*)(xrow + k);
#pragma unroll
    for (int e = 0; e < NEXP; e++) {
      float4 wv = *(const float4*)(wr + e * HID + k);
      acc[e] += xv.x * wv.x + xv.y * wv.y + xv.z * wv.z + xv.w * wv.w;
    }
  }
#pragma unroll
  for (int e = 0; e < NEXP; e++) {
    float v = acc[e];
    for (int off = 32; off; off >>= 1) v += __shfl_xor(v, off, 64);
    acc[e] = v;
  }
  if (lane == 0) {
    float m = acc[0];
#pragma unroll
    for (int e = 1; e < NEXP; e++) m = fmaxf(m, acc[e]);
    float p[NEXP], s = 0.f;
#pragma unroll
    for (int e = 0; e < NEXP; e++) { p[e] = __expf(acc[e] - m); s += p[e]; }
    const float inv = 1.f / s;
    int e1 = 0; float b1 = p[0];
#pragma unroll
    for (int e = 1; e < NEXP; e++) if (p[e] > b1) { b1 = p[e]; e1 = e; }
    int e2 = -1; float b2 = -1.f;
#pragma unroll
    for (int e = 0; e < NEXP; e++) if (e != e1 && p[e] > b2) { b2 = p[e]; e2 = e; }
    const int pos1 = atomicAdd(&cnt[e1], 1);
    lists[e1 * NTOK + pos1] = t; wlists[e1 * NTOK + pos1] = b1 * inv;
    const int pos2 = atomicAdd(&cnt[e2], 1);
    lists[e2 * NTOK + pos2] = t; wlists[e2 * NTOK + pos2] = b2 * inv;
  }
}

__global__ void offsets_kernel(const int* __restrict__ cnt, int* __restrict__ poffs) {
  if (threadIdx.x == 0 && blockIdx.x == 0) {
    int o = 0;
#pragma unroll
    for (int e = 0; e < NEXP; e++) { poffs[e] = o; o += ((cnt[e] + 255) >> 8) << 8; }
    poffs[NEXP] = o;
  }
}

// ---------------- slotmap ----------------
__global__ void slotmap_kernel(const int* __restrict__ cnt, const int* __restrict__ poffs,
                               const int* __restrict__ lists, const float* __restrict__ wlists,
                               int* __restrict__ slotlist, int* __restrict__ tcnt,
                               int* __restrict__ tok2slot, float* __restrict__ w2) {
  const int e = blockIdx.x;
  const int c = cnt[e], base = poffs[e];
  for (int pos = threadIdx.x; pos < c; pos += blockDim.x) {
    const int tok = lists[e * NTOK + pos];
    const int slot = base + pos;
    slotlist[slot] = tok;
    const int j = atomicAdd(&tcnt[tok], 1);
    tok2slot[tok * 2 + j] = slot;
    w2[tok * 2 + j] = wlists[e * NTOK + pos];
  }
}

// ---------------- gather: x (f32) -> xg bf16 in A-fragment layout ----------------
__global__ __launch_bounds__(256, 4) void gather_kernel(
    const float* __restrict__ x, const int* __restrict__ slotlist,
    short* __restrict__ xg) {
  const int c = blockIdx.x * 256 + threadIdx.x;
  const int cl = c & 63;
  const int fragid = c >> 6;
  const int f = fragid & 15;
  const int kt = (fragid >> 4) & 63;
  const int gmt = fragid >> 10;
  const int tok = slotlist[gmt * 256 + f * 16 + (cl & 15)];
  const float* s = x + (size_t)tok * HID + kt * 32 + (cl >> 4) * 8;
  float4 a = *(const float4*)s, b = *(const float4*)(s + 4);
  *(s16x8*)(xg + (size_t)c * 8) = pk8(a, b);
}

// ---------------- gemm1: homogeneous reg-load stream ----------------
// 256x128, 8 waves. A frags global->VGPR (dbuf). B (gate+up) global->VGPR one step
// ahead, ds_write into 2-deep LDS buffer next body. ALL vmem = global_load_dwordx4
// (in-order vmcnt, m135) -> exact counted waits are safe.
__global__ __launch_bounds__(512, 2) void gemm1_kernel(
    const short* __restrict__ xg, const short* __restrict__ wgb,
    const short* __restrict__ wub, const int* __restrict__ cnt,
    const int* __restrict__ poffs, short* __restrict__ hfrag) {
  const int P = blockIdx.x;
  const int xcd = P & 7, slot = P >> 3;
  const int mt = slot & 31, jj = slot >> 5;
  const int g = jj * 8 + xcd;                 // (e,nt) group pinned to xcd
  const int e = g / NT1, nt = g % NT1;
  if (mt * 256 >= cnt[e]) return;
  const int gmt = (poffs[e] >> 8) + mt;
  const int tid = threadIdx.x;
  const int w = tid >> 6, lane = tid & 63;
  const int wm = w >> 1, wn = w & 1;

  // loop: 2 bufs x 16384 B (Bg 8KB | Bu 8KB); epilogue: 256x136 transpose (69632 B)
  __shared__ __align__(16) short Lds[34816];
  const uint32_t ldsbase = (uint32_t)(uintptr_t)&Lds[0];

  const short* srcA  = xg + (size_t)gmt * 64 * 16 * 512 + (size_t)(wm * 4) * 512 + lane * 8;
  const short* srcBg = wgb + (((size_t)e * 64) * 352 + nt * 8) * 512 + tid * 8;
  const short* srcBu = wub + (((size_t)e * 64) * 352 + nt * 8) * 512 + tid * 8;

  const uint32_t roB = wn * 4096 + lane * 16;          // within buffer (bytes)
  const uint32_t roU = 8192 + wn * 4096 + lane * 16;
  const uint32_t awr = ldsbase + tid * 16;             // ds_write base (buf0 Bg)

  f32x4 accG[4][4], accU[4][4];
#pragma unroll
  for (int i = 0; i < 4; i++)
#pragma unroll
    for (int j = 0; j < 4; j++) {
      accG[i][j] = f32x4{0.f, 0.f, 0.f, 0.f};
      accU[i][j] = f32x4{0.f, 0.f, 0.f, 0.f};
    }

  s16x8 arA0, arA1, arA2, arA3, arB0, arB1, arB2, arB3;  // A dbuf reg sets
  s16x8 g0p, u0p, g1p, u1p;                              // B in-flight pairs

  // prologue: B(0)->pair0, A(0)->arA, B(1)->pair1; write stage0 -> buf0
  LOADB2(g0p, u0p, srcBg, srcBu); srcBg += 180224; srcBu += 180224;
  LOADA4(arA0, arA1, arA2, arA3, srcA); srcA += 8192;
  LOADB2(g1p, u1p, srcBg, srcBu); srcBg += 180224; srcBu += 180224;
  WAITVM(6);                       // pair0 regs ready
  DSW128(awr, g0p, "0");
  DSW128(awr, u0p, "8192");
  WAITLGKM(0);
  // queue: [A(0) x4, B(1) x2]

#define MMQ(NF, BG, BU, A0, A1, A2, A3)                                         \
  { __builtin_amdgcn_s_setprio(1);                                              \
    accG[0][NF] = MFMA_BF16(A0, BG, accG[0][NF], 0, 0, 0);                      \
    accU[0][NF] = MFMA_BF16(A0, BU, accU[0][NF], 0, 0, 0);                      \
    accG[1][NF] = MFMA_BF16(A1, BG, accG[1][NF], 0, 0, 0);                      \
    accU[1][NF] = MFMA_BF16(A1, BU, accU[1][NF], 0, 0, 0);                      \
    accG[2][NF] = MFMA_BF16(A2, BG, accG[2][NF], 0, 0, 0);                      \
    accU[2][NF] = MFMA_BF16(A2, BU, accU[2][NF], 0, 0, 0);                      \
    accG[3][NF] = MFMA_BF16(A3, BG, accG[3][NF], 0, 0, 0);                      \
    accU[3][NF] = MFMA_BF16(A3, BU, accU[3][NF], 0, 0, 0);                      \
    __builtin_amdgcn_s_setprio(0); }

#define G1_BODY(RBOFF, WIG, WIU, U0,U1,U2,U3, L0,L1,L2,L3, WPG,WPU, LPG,LPU,    \
                VTOP, DO_A, DO_WR, DO_LB, LGA, LGB, LGC, LGD)                   \
  {                                                                             \
    WAITVM(VTOP);                       /* U-set A regs ready */                \
    __builtin_amdgcn_s_barrier();       /* buf(t) fully written */              \
    const uint32_t rb = ldsbase + (RBOFF);                                      \
    s16x8 bg0, bg1, bg2, bg3, bu0, bu1, bu2, bu3;                               \
    DSR128(bg0, rb + roB, "0");    DSR128(bu0, rb + roU, "0");                  \
    DSR128(bg1, rb + roB, "1024"); DSR128(bu1, rb + roU, "1024");               \
    DSR128(bg2, rb + roB, "2048"); DSR128(bu2, rb + roU, "2048");               \
    DSR128(bg3, rb + roB, "3072"); DSR128(bu3, rb + roU, "3072");               \
    if (DO_A) { LOADA4(L0, L1, L2, L3, srcA); srcA += 8192; }                   \
    if (DO_WR) {                                                                \
      WAITVM(4);                        /* write-pair regs ready */             \
      DSW128(awr, WPG, WIG);                                                    \
      DSW128(awr, WPU, WIU);                                                    \
    }                                                                           \
    if (DO_LB) { LOADB2(LPG, LPU, srcBg, srcBu);                                \
                 srcBg += 180224; srcBu += 180224; }                            \
    WAITLGKM(LGA);                                                              \
    MMQ(0, bg0, bu0, U0, U1, U2, U3)                                            \
    WAITLGKM(LGB);                                                              \
    MMQ(1, bg1, bu1, U0, U1, U2, U3)                                            \
    WAITLGKM(LGC);                                                              \
    MMQ(2, bg2, bu2, U0, U1, U2, U3)                                            \
    WAITLGKM(LGD);                                                              \
    MMQ(3, bg3, bu3, U0, U1, U2, U3)                                            \
    WAITLGKM(0);                        /* drain ds_writes before next barrier */ \
  }

  for (int it = 0; it < 31; ++it) {   // t = 0..61
    G1_BODY(0,     "16384","24576", arA0,arA1,arA2,arA3, arB0,arB1,arB2,arB3,
            g1p,u1p, g0p,u0p, 2, 1, 1, 1, 8, 6, 4, 2)
    G1_BODY(16384, "0","8192",      arB0,arB1,arB2,arB3, arA0,arA1,arA2,arA3,
            g0p,u0p, g1p,u1p, 2, 1, 1, 1, 8, 6, 4, 2)
  }
  // t=62 (even): no B load (step 64 doesn't exist)
  G1_BODY(0,     "16384","24576", arA0,arA1,arA2,arA3, arB0,arB1,arB2,arB3,
          g1p,u1p, g0p,u0p, 2, 1, 1, 0, 8, 6, 4, 2)
  // t=63 (odd): no A load, no write, no B load
  G1_BODY(16384, "0","8192",      arB0,arB1,arB2,arB3, arA0,arA1,arA2,arA3,
          g0p,u0p, g1p,u1p, 0, 0, 0, 0, 6, 4, 2, 0)
#undef G1_BODY
#undef MMQ

  // epilogue: silu-gate, LDS transpose 256x128 (pad 136), store gemm2 A-frag layout
  short* tr = (short*)Lds;
  __syncthreads();
#pragma unroll
  for (int mf = 0; mf < 4; mf++)
#pragma unroll
    for (int reg = 0; reg < 4; reg++) {
      const int row = wm * 64 + mf * 16 + (lane >> 4) * 4 + reg;
#pragma unroll
      for (int nf = 0; nf < 4; nf++) {
        const int col = wn * 64 + nf * 16 + (lane & 15);
        const float gv = accG[mf][nf][reg];
        const float uv = accU[mf][nf][reg];
        tr[row * 136 + col] = bfc((gv / (1.f + __expf(-gv))) * uv);
      }
    }
  __syncthreads();
  short* hb = hfrag + (((size_t)gmt * 176 + nt * 4) * 16) * 512;
#pragma unroll
  for (int i = 0; i < 8; i++) {
    const int c = tid + i * 512;             // 0..4095
    const int cl = c & 63;
    const int f = (c >> 6) & 15;
    const int ktl = c >> 10;                 // 0..3
    const int rr = f * 16 + (cl & 15);
    s16x8 v = *(const s16x8*)(tr + rr * 136 + ktl * 32 + (cl >> 4) * 8);
    *(s16x8*)(hb + ((size_t)ktl * 16 + f) * 512 + cl * 8) = v;
  }
}

// ---------------- gemm2: round-6 proven version (pure gload16, triple buffer) -----
__global__ __launch_bounds__(512, 4) void gemm2_kernel(
    const short* __restrict__ hfrag, const short* __restrict__ wdb,
    const int* __restrict__ cnt, const int* __restrict__ poffs,
    __hip_bfloat16* __restrict__ pout) {
  const int P = blockIdx.x;
  const int xcd = P & 7, r = P >> 3;
  const int nt = r & 15, emq = r >> 4;
  const int gm = emq * 8 + xcd;              // m-tile pinned to xcd
  const int e = gm >> 5, mt = gm & 31;
  if (mt * 256 >= cnt[e]) return;
  const int gmt = (poffs[e] >> 8) + mt;
  const int n0 = nt * 128;
  const int tid = threadIdx.x;
  const int w = tid >> 6, lane = tid & 63;
  const int wm = w >> 1, wn = w & 1;

  // per buffer (12288 shorts = 24KB): A 16 frags [0,8192), B 8 frags [8192,12288)
  __shared__ __align__(16) short Lds[3 * 12288];
  const uint32_t ldsbase = (uint32_t)(uintptr_t)&Lds[0];

  const short* srcA = hfrag + (size_t)gmt * 176 * 16 * 512 + tid * 8;
  const short* srcB = wdb + (((size_t)e * 176) * 128 + nt * 8) * 512 + tid * 8;

  const uint32_t roA = wm * 4096 + lane * 16;
  const uint32_t roB = 16384 + wn * 4096 + lane * 16;

  f32x4 acc[4][4];
#pragma unroll
  for (int i = 0; i < 4; i++)
#pragma unroll
    for (int j = 0; j < 4; j++) acc[i][j] = f32x4{0.f, 0.f, 0.f, 0.f};

#define STG2(WB) do {                                                           \
    short* d = (short*)Lds + ((WB) >> 1);                                       \
    gload16(srcA,        d + w * 512);                                          \
    gload16(srcA + 4096, d + 4096 + w * 512);                                   \
    gload16(srcB,        d + 8192 + w * 512);                                   \
    srcA += 8192; srcB += 65536; } while (0)

#define MMQ2(NF, BF)                                                            \
  { __builtin_amdgcn_s_setprio(1);                                              \
    acc[0][NF] = MFMA_BF16(af0, BF, acc[0][NF], 0, 0, 0);                       \
    acc[1][NF] = MFMA_BF16(af1, BF, acc[1][NF], 0, 0, 0);                       \
    acc[2][NF] = MFMA_BF16(af2, BF, acc[2][NF], 0, 0, 0);                       \
    acc[3][NF] = MFMA_BF16(af3, BF, acc[3][NF], 0, 0, 0);                       \
    __builtin_amdgcn_s_setprio(0); }

#define G2_BODY(RB, WB, VMN, DOSTG)                                             \
  {                                                                             \
    WAITVM(VMN);                                                                \
    __builtin_amdgcn_s_barrier();                                               \
    const uint32_t rb = ldsbase + (RB);                                         \
    s16x8 af0, af1, af2, af3, bf0, bf1, bf2, bf3;                               \
    DSR128(bf0, rb + roB, "0");                                                 \
    DSR128(af0, rb + roA, "0");    DSR128(af1, rb + roA, "1024");               \
    DSR128(af2, rb + roA, "2048"); DSR128(af3, rb + roA, "3072");               \
    DSR128(bf1, rb + roB, "1024");                                              \
    DSR128(bf2, rb + roB, "2048");                                              \
    DSR128(bf3, rb + roB, "3072");                                              \
    if (DOSTG) { STG2(WB); }                                                    \
    WAITLGKM(3);                                                                \
    MMQ2(0, bf0)                                                                \
    WAITLGKM(2);                                                                \
    MMQ2(1, bf1)                                                                \
    WAITLGKM(1);                                                                \
    MMQ2(2, bf2)                                                                \
    WAITLGKM(0);                                                                \
    MMQ2(3, bf3)                                                                \
  }

  STG2(0);
  STG2(24576);
  for (int it = 0; it < 58; ++it) {          // t = 0..173
    G2_BODY(0,     49152, 3, 1)
    G2_BODY(24576, 0,     3, 1)
    G2_BODY(49152, 24576, 3, 1)
  }
  G2_BODY(0,     0, 3, 0)                    // t=174
  G2_BODY(24576, 0, 0, 0)                    // t=175
#undef G2_BODY
#undef MMQ2
#undef STG2

  const int slotb = poffs[e] + mt * 256;
#pragma unroll
  for (int mf = 0; mf < 4; mf++) {
#pragma unroll
    for (int reg = 0; reg < 4; reg++) {
      const int row = wm * 64 + mf * 16 + (lane >> 4) * 4 + reg;
      __hip_bfloat16* op = pout + (size_t)(slotb + row) * HID + n0 + wn * 64 + (lane & 15);
#pragma unroll
      for (int nf = 0; nf < 4; nf++)
        op[nf * 16] = __float2bfloat16(acc[mf][nf][reg]);
    }
  }
}

// ---------------- combine ----------------
__global__ __launch_bounds__(256, 8) void combine_kernel(
    const __hip_bfloat16* __restrict__ pout, const int* __restrict__ tok2slot,
    const float* __restrict__ w2, float* __restrict__ out) {
  const int t = blockIdx.x;
  const int s0 = tok2slot[2 * t], s1 = tok2slot[2 * t + 1];
  const float w0 = w2[2 * t], w1 = w2[2 * t + 1];
  const short* p0 = (const short*)pout + (size_t)s0 * HID;
  const short* p1 = (const short*)pout + (size_t)s1 * HID;
  float* o = out + (size_t)t * HID;
  const int i = threadIdx.x;
  s16x8 a = *(const s16x8*)(p0 + i * 8);
  s16x8 b = *(const s16x8*)(p1 + i * 8);
  float4 r0, r1;
  r0.x = w0 * b2f(a[0]) + w1 * b2f(b[0]);
  r0.y = w0 * b2f(a[1]) + w1 * b2f(b[1]);
  r0.z = w0 * b2f(a[2]) + w1 * b2f(b[2]);
  r0.w = w0 * b2f(a[3]) + w1 * b2f(b[3]);
  r1.x = w0 * b2f(a[4]) + w1 * b2f(b[4]);
  r1.y = w0 * b2f(a[5]) + w1 * b2f(b[5]);
  r1.z = w0 * b2f(a[6]) + w1 * b2f(b[6]);
  r1.w = w0 * b2f(a[7]) + w1 * b2f(b[7]);
  *(float4*)(o + i * 8) = r0;
  *(float4*)(o + i * 8 + 4) = r1;
}

extern "C" void kernel_launch(void* const* d_in, const int* in_sizes, int n_in,
                              void* d_out, int out_size, void* d_ws, size_t ws_size,
                              hipStream_t stream) {
  const float* x  = (const float*)d_in[0];
  const float* wr = (const float*)d_in[1];
  const float* wg = (const float*)d_in[2];
  const float* wu = (const float*)d_in[3];
  const float* wd = (const float*)d_in[4];
  float* out = (float*)d_out;
  char* ws = (char*)d_ws;

  int* cnt      = (int*)ws;
  int* poffs    = (int*)(ws + 64);
  int* tcnt     = (int*)(ws + TCNT_OFF);
  int* slotlist = (int*)(ws + SLOT_OFF);
  int* tok2slot = (int*)(ws + T2S_OFF);
  float* w2     = (float*)(ws + W2_OFF);
  int* lists    = (int*)(ws + LISTS_OFF);
  float* wlists = (float*)(ws + WL_OFF);
  short* wgb    = (short*)(ws + WG_OFF);
  short* wub    = (short*)(ws + WU_OFF);
  short* wdb    = (short*)(ws + WG_OFF);     // reuses wgb region (after gemm1)
  short* hfrag  = (short*)(ws + HF_OFF);
  short* xg     = (short*)(ws + XG_OFF);
  __hip_bfloat16* pout = (__hip_bfloat16*)(ws + XG_OFF);  // reuses xg (after gemm1)

  hipMemsetAsync(ws, 0, 256, stream);
  hipMemsetAsync(ws + TCNT_OFF, 0, 32768, stream);
  hipMemsetAsync(ws + SLOT_OFF, 0, 73728, stream);

  router_kernel<<<NTOK / 4, 256, 0, stream>>>(x, wr, cnt, lists, wlists);
  offsets_kernel<<<1, 64, 0, stream>>>(cnt, poffs);
  slotmap_kernel<<<NEXP, 256, 0, stream>>>(cnt, poffs, lists, wlists, slotlist, tcnt, tok2slot, w2);
  gather_kernel<<<18432, 256, 0, stream>>>(x, slotlist, xg);
  prep_kernel<<<NEXP * 64 * 44, 256, 0, stream>>>(wg, wgb, 64, 44, INTR);
  prep_kernel<<<NEXP * 64 * 44, 256, 0, stream>>>(wu, wub, 64, 44, INTR);
  gemm1_kernel<<<8 * 32 * NT1, 512, 0, stream>>>(xg, wgb, wub, cnt, poffs, hfrag);
  prep_kernel<<<NEXP * 176 * 16, 256, 0, stream>>>(wd, wdb, 176, 16, HID);
  gemm2_kernel<<<8 * 16 * 32, 512, 0, stream>>>(hfrag, wdb, cnt, poffs, pout);
  combine_kernel<<<NTOK, 256, 0, stream>>>(pout, tok2slot, w2, out);
}

// Round 9
// 1677.474 us; speedup vs baseline: 1.0613x; 1.0613x over previous
//
#include <hip/hip_runtime.h>
#include <hip/hip_bf16.h>
#include <cstdint>

#define NTOK 8192
#define NEXP 8
#define HID  2048
#define INTR 5632
#define NT1  44     // INTR/128 n-tiles for gemm1
#define NT2  16     // HID/128  n-tiles for gemm2

// ws offsets (bytes)
#define TCNT_OFF    4096u
#define SLOT_OFF    65536u      // slotlist: 18432 ints
#define T2S_OFF     262144u     // tok2slot: 32768 ints
#define W2_OFF      393216u     // w2: 32768 floats
#define LISTS_OFF   524288u     // lists: 65536 ints
#define WL_OFF      786432u     // wlists: 65536 floats
#define WG_OFF      2097152u
#define WBYTES      184549376u
#define WU_OFF      (WG_OFF + WBYTES)
#define HF_OFF      (WU_OFF + WBYTES)
#define HFBYTES     207618048u  // 72 mtiles * 176 kt * 16 frags * 1024 B
#define XG_OFF      (HF_OFF + HFBYTES)   // xg (75.5MB) then reused as pout

typedef float f32x4  __attribute__((ext_vector_type(4)));
typedef short s16x8  __attribute__((ext_vector_type(8)));
typedef short s16x4  __attribute__((ext_vector_type(4)));

__device__ __forceinline__ short bfc(float f) {
  __hip_bfloat16 h = __float2bfloat16(f);
  return __builtin_bit_cast(short, h);
}
__device__ __forceinline__ float b2f(short s) {
  unsigned u = ((unsigned)(unsigned short)s) << 16;
  return __builtin_bit_cast(float, u);
}
__device__ __forceinline__ s16x8 pk8(float4 a, float4 b) {
  s16x8 v;
  v[0]=bfc(a.x); v[1]=bfc(a.y); v[2]=bfc(a.z); v[3]=bfc(a.w);
  v[4]=bfc(b.x); v[5]=bfc(b.y); v[6]=bfc(b.z); v[7]=bfc(b.w);
  return v;
}
__device__ __forceinline__ void gload16(const void* g, void* l) {
  __builtin_amdgcn_global_load_lds((const __attribute__((address_space(1))) void*)g,
                                   (__attribute__((address_space(3))) void*)l, 16, 0, 0);
}

#define DSR128(dst, addr, IMM) \
  asm volatile("ds_read_b128 %0, %1 offset:" IMM : "=v"(dst) : "v"(addr))
#define WAITLGKM(N) do { \
  asm volatile("s_waitcnt lgkmcnt(" #N ")" ::: "memory"); \
  __builtin_amdgcn_sched_barrier(0); } while (0)
#define WAITVM(N) do { \
  asm volatile("s_waitcnt vmcnt(" #N ")" ::: "memory"); \
  __builtin_amdgcn_sched_barrier(0); } while (0)

// 4 A-fragment loads global->VGPR (frag stride 1024B), async; completion via WAITVM
#define LOADA4(D0, D1, D2, D3, PTR) \
  asm volatile("global_load_dwordx4 %0, %4, off\n\t" \
               "global_load_dwordx4 %1, %4, off offset:1024\n\t" \
               "global_load_dwordx4 %2, %4, off offset:2048\n\t" \
               "global_load_dwordx4 %3, %4, off offset:3072" \
               : "=&v"(D0), "=&v"(D1), "=&v"(D2), "=&v"(D3) : "v"(PTR))

#define MFMA_BF16 __builtin_amdgcn_mfma_f32_16x16x32_bf16

// ---------------- prep: f32 weights -> bf16 MFMA B-fragment layout ----------------
__global__ __launch_bounds__(256, 4) void prep_kernel(
    const float* __restrict__ src, short* __restrict__ dst,
    int KT, int NP, int Nsrc) {
  __shared__ float tile[32 * 132];
  const int b = blockIdx.x;
  const int np = b % NP;
  const int kt = (b / NP) % KT;
  const int e  = b / (NP * KT);
  const int tid = threadIdx.x;
  const float* s = src + (size_t)e * KT * 32 * (size_t)Nsrc + (size_t)kt * 32 * Nsrc + np * 128;
#pragma unroll
  for (int i = 0; i < 4; i++) {
    const int idx = tid + i * 256;
    const int row = idx >> 5, c4 = idx & 31;
    float4 v = *(const float4*)(s + (size_t)row * Nsrc + c4 * 4);
    *(float4*)(tile + row * 132 + c4 * 4) = v;
  }
  __syncthreads();
  short* dbase = dst + ((size_t)(e * KT + kt) * (NP * 8) + np * 8) * 512;
#pragma unroll
  for (int i = 0; i < 2; i++) {
    const int c = tid + i * 256;
    const int lane = c & 63;
    const int nf = c >> 6;
    const int n = nf * 16 + (lane & 15);
    const int kb = (lane >> 4) * 8;
    s16x8 o;
#pragma unroll
    for (int j = 0; j < 8; j++) o[j] = bfc(tile[(kb + j) * 132 + n]);
    *(s16x8*)(dbase + (size_t)c * 8) = o;
  }
}

// ---------------- router ----------------
__global__ void router_kernel(const float* __restrict__ x, const float* __restrict__ wr,
                              int* __restrict__ cnt, int* __restrict__ lists,
                              float* __restrict__ wlists) {
  const int wave = threadIdx.x >> 6;
  const int lane = threadIdx.x & 63;
  const int t = blockIdx.x * 4 + wave;
  if (t >= NTOK) return;
  float acc[NEXP];
#pragma unroll
  for (int e = 0; e < NEXP; e++) acc[e] = 0.f;
  const float* xrow = x + (size_t)t * HID;
#pragma unroll
  for (int j = 0; j < HID / 256; j++) {
    const int k = j * 256 + lane * 4;
    float4 xv = *(const float4*)(xrow + k);
#pragma unroll
    for (int e = 0; e < NEXP; e++) {
      float4 wv = *(const float4*)(wr + e * HID + k);
      acc[e] += xv.x * wv.x + xv.y * wv.y + xv.z * wv.z + xv.w * wv.w;
    }
  }
#pragma unroll
  for (int e = 0; e < NEXP; e++) {
    float v = acc[e];
    for (int off = 32; off; off >>= 1) v += __shfl_xor(v, off, 64);
    acc[e] = v;
  }
  if (lane == 0) {
    float m = acc[0];
#pragma unroll
    for (int e = 1; e < NEXP; e++) m = fmaxf(m, acc[e]);
    float p[NEXP], s = 0.f;
#pragma unroll
    for (int e = 0; e < NEXP; e++) { p[e] = __expf(acc[e] - m); s += p[e]; }
    const float inv = 1.f / s;
    int e1 = 0; float b1 = p[0];
#pragma unroll
    for (int e = 1; e < NEXP; e++) if (p[e] > b1) { b1 = p[e]; e1 = e; }
    int e2 = -1; float b2 = -1.f;
#pragma unroll
    for (int e = 0; e < NEXP; e++) if (e != e1 && p[e] > b2) { b2 = p[e]; e2 = e; }
    const int pos1 = atomicAdd(&cnt[e1], 1);
    lists[e1 * NTOK + pos1] = t; wlists[e1 * NTOK + pos1] = b1 * inv;
    const int pos2 = atomicAdd(&cnt[e2], 1);
    lists[e2 * NTOK + pos2] = t; wlists[e2 * NTOK + pos2] = b2 * inv;
  }
}

__global__ void offsets_kernel(const int* __restrict__ cnt, int* __restrict__ poffs) {
  if (threadIdx.x == 0 && blockIdx.x == 0) {
    int o = 0;
#pragma unroll
    for (int e = 0; e < NEXP; e++) { poffs[e] = o; o += ((cnt[e] + 255) >> 8) << 8; }
    poffs[NEXP] = o;
  }
}

// ---------------- slotmap ----------------
__global__ void slotmap_kernel(const int* __restrict__ cnt, const int* __restrict__ poffs,
                               const int* __restrict__ lists, const float* __restrict__ wlists,
                               int* __restrict__ slotlist, int* __restrict__ tcnt,
                               int* __restrict__ tok2slot, float* __restrict__ w2) {
  const int e = blockIdx.x;
  const int c = cnt[e], base = poffs[e];
  for (int pos = threadIdx.x; pos < c; pos += blockDim.x) {
    const int tok = lists[e * NTOK + pos];
    const int slot = base + pos;
    slotlist[slot] = tok;
    const int j = atomicAdd(&tcnt[tok], 1);
    tok2slot[tok * 2 + j] = slot;
    w2[tok * 2 + j] = wlists[e * NTOK + pos];
  }
}

// ---------------- gather: x (f32) -> xg bf16 in A-fragment layout ----------------
__global__ __launch_bounds__(256, 4) void gather_kernel(
    const float* __restrict__ x, const int* __restrict__ slotlist,
    short* __restrict__ xg) {
  const int c = blockIdx.x * 256 + threadIdx.x;
  const int cl = c & 63;
  const int fragid = c >> 6;
  const int f = fragid & 15;
  const int kt = (fragid >> 4) & 63;
  const int gmt = fragid >> 10;
  const int tok = slotlist[gmt * 256 + f * 16 + (cl & 15)];
  const float* s = x + (size_t)tok * HID + kt * 32 + (cl >> 4) * 8;
  float4 a = *(const float4*)s, b = *(const float4*)(s + 4);
  *(s16x8*)(xg + (size_t)c * 8) = pk8(a, b);
}

// ---------------- gemm1: A frags direct global->VGPR (dbuf regs), B via LDS -------
// 256x128 tile, 8 waves (4Mx2N). LDS = B only, 3 x 16KB, counted mixed-queue vmcnt:
// steady queue [S(t)x2, A(t)x4, S(t+1)x2]; VTOP=6 -> buf(t) DMA done (2 bodies old);
// VMID=8 -> A(t) regs done (issued last body). LDS reads/CU/step: 96 -> 64.
__global__ __launch_bounds__(512, 2) void gemm1_kernel(
    const short* __restrict__ xg, const short* __restrict__ wgb,
    const short* __restrict__ wub, const int* __restrict__ cnt,
    const int* __restrict__ poffs, short* __restrict__ hfrag) {
  const int P = blockIdx.x;
  const int xcd = P & 7, slot = P >> 3;
  const int mt = slot & 31, jj = slot >> 5;
  const int g = jj * 8 + xcd;                 // (e,nt) group pinned to xcd
  const int e = g / NT1, nt = g % NT1;
  if (mt * 256 >= cnt[e]) return;
  const int gmt = (poffs[e] >> 8) + mt;
  const int tid = threadIdx.x;
  const int w = tid >> 6, lane = tid & 63;
  const int wm = w >> 1, wn = w & 1;

  // loop: 3 bufs x 16384 B (Bg 8KB | Bu 8KB); epilogue: 256x136 transpose
  __shared__ __align__(16) short Lds[34816];
  const uint32_t ldsbase = (uint32_t)(uintptr_t)&Lds[0];

  const short* srcA  = xg + (size_t)gmt * 64 * 16 * 512 + (size_t)(wm * 4) * 512 + lane * 8;
  const short* srcBg = wgb + (((size_t)e * 64) * 352 + nt * 8) * 512 + tid * 8;
  const short* srcBu = wub + (((size_t)e * 64) * 352 + nt * 8) * 512 + tid * 8;

  const uint32_t roB = wn * 4096 + lane * 16;
  const uint32_t roU = 8192 + wn * 4096 + lane * 16;

  f32x4 accG[4][4], accU[4][4];
#pragma unroll
  for (int i = 0; i < 4; i++)
#pragma unroll
    for (int j = 0; j < 4; j++) {
      accG[i][j] = f32x4{0.f, 0.f, 0.f, 0.f};
      accU[i][j] = f32x4{0.f, 0.f, 0.f, 0.f};
    }

  s16x8 arA0, arA1, arA2, arA3, arB0, arB1, arB2, arB3;

#define STG1(WB) do {                                                           \
    short* d = (short*)Lds + ((WB) >> 1);                                       \
    gload16(srcBg, d + w * 512);                                                \
    gload16(srcBu, d + 4096 + w * 512);                                         \
    srcBg += 180224; srcBu += 180224; } while (0)

#define MMQ1(NF, BG, BU, A0, A1, A2, A3)                                        \
  { __builtin_amdgcn_s_setprio(1);                                              \
    accG[0][NF] = MFMA_BF16(A0, BG, accG[0][NF], 0, 0, 0);                      \
    accU[0][NF] = MFMA_BF16(A0, BU, accU[0][NF], 0, 0, 0);                      \
    accG[1][NF] = MFMA_BF16(A1, BG, accG[1][NF], 0, 0, 0);                      \
    accU[1][NF] = MFMA_BF16(A1, BU, accU[1][NF], 0, 0, 0);                      \
    accG[2][NF] = MFMA_BF16(A2, BG, accG[2][NF], 0, 0, 0);                      \
    accU[2][NF] = MFMA_BF16(A2, BU, accU[2][NF], 0, 0, 0);                      \
    accG[3][NF] = MFMA_BF16(A3, BG, accG[3][NF], 0, 0, 0);                      \
    accU[3][NF] = MFMA_BF16(A3, BU, accU[3][NF], 0, 0, 0);                      \
    __builtin_amdgcn_s_setprio(0); }

#define G1_BODY(RB, WB, U0, U1, U2, U3, L0, L1, L2, L3, VTOP, VMID, DO_A, DO_STG) \
  {                                                                             \
    WAITVM(VTOP);                                                               \
    __builtin_amdgcn_s_barrier();                                               \
    const uint32_t rb = ldsbase + (RB);                                         \
    s16x8 bg0, bg1, bg2, bg3, bu0, bu1, bu2, bu3;                               \
    DSR128(bg0, rb + roB, "0");    DSR128(bu0, rb + roU, "0");                  \
    DSR128(bg1, rb + roB, "1024"); DSR128(bu1, rb + roU, "1024");               \
    DSR128(bg2, rb + roB, "2048"); DSR128(bu2, rb + roU, "2048");               \
    DSR128(bg3, rb + roB, "3072"); DSR128(bu3, rb + roU, "3072");               \
    if (DO_A) { LOADA4(L0, L1, L2, L3, srcA); srcA += 8192; }                   \
    if (DO_STG) { STG1(WB); }                                                   \
    WAITVM(VMID);                                                               \
    WAITLGKM(6);                                                                \
    MMQ1(0, bg0, bu0, U0, U1, U2, U3)                                           \
    WAITLGKM(4);                                                                \
    MMQ1(1, bg1, bu1, U0, U1, U2, U3)                                           \
    WAITLGKM(2);                                                                \
    MMQ1(2, bg2, bu2, U0, U1, U2, U3)                                           \
    WAITLGKM(0);                                                                \
    MMQ1(3, bg3, bu3, U0, U1, U2, U3)                                           \
  }

  // prologue: stg(0)->buf0, A(0)->arA, stg(1)->buf1   (outstanding: 2+4+2)
  STG1(0);
  LOADA4(arA0, arA1, arA2, arA3, srcA); srcA += 8192;
  STG1(16384);

  for (int it = 0; it < 10; ++it) {            // t = 0..59
    G1_BODY(0,     32768, arA0,arA1,arA2,arA3, arB0,arB1,arB2,arB3, 6, 8, 1, 1)
    G1_BODY(16384, 0,     arB0,arB1,arB2,arB3, arA0,arA1,arA2,arA3, 6, 8, 1, 1)
    G1_BODY(32768, 16384, arA0,arA1,arA2,arA3, arB0,arB1,arB2,arB3, 6, 8, 1, 1)
    G1_BODY(0,     32768, arB0,arB1,arB2,arB3, arA0,arA1,arA2,arA3, 6, 8, 1, 1)
    G1_BODY(16384, 0,     arA0,arA1,arA2,arA3, arB0,arB1,arB2,arB3, 6, 8, 1, 1)
    G1_BODY(32768, 16384, arB0,arB1,arB2,arB3, arA0,arA1,arA2,arA3, 6, 8, 1, 1)
  }
  G1_BODY(0,     32768, arA0,arA1,arA2,arA3, arB0,arB1,arB2,arB3, 6, 8, 1, 1)   // t=60
  G1_BODY(16384, 0,     arB0,arB1,arB2,arB3, arA0,arA1,arA2,arA3, 6, 8, 1, 1)   // t=61
  G1_BODY(32768, 0,     arA0,arA1,arA2,arA3, arB0,arB1,arB2,arB3, 6, 6, 1, 0)   // t=62
  G1_BODY(0,     0,     arB0,arB1,arB2,arB3, arA0,arA1,arA2,arA3, 4, 0, 0, 0)   // t=63
#undef G1_BODY
#undef MMQ1
#undef STG1

  // epilogue: silu-gate, LDS transpose 256x128 (pad 136), store gemm2 A-frag layout
  short* tr = (short*)Lds;                   // 256*136 shorts = 69632 B
  __syncthreads();
#pragma unroll
  for (int mf = 0; mf < 4; mf++)
#pragma unroll
    for (int reg = 0; reg < 4; reg++) {
      const int row = wm * 64 + mf * 16 + (lane >> 4) * 4 + reg;
#pragma unroll
      for (int nf = 0; nf < 4; nf++) {
        const int col = wn * 64 + nf * 16 + (lane & 15);
        const float gv = accG[mf][nf][reg];
        const float uv = accU[mf][nf][reg];
        tr[row * 136 + col] = bfc((gv / (1.f + __expf(-gv))) * uv);
      }
    }
  __syncthreads();
  short* hb = hfrag + (((size_t)gmt * 176 + nt * 4) * 16) * 512;
#pragma unroll
  for (int i = 0; i < 8; i++) {
    const int c = tid + i * 512;             // 0..4095
    const int cl = c & 63;
    const int f = (c >> 6) & 15;
    const int ktl = c >> 10;                 // 0..3
    const int rr = f * 16 + (cl & 15);
    s16x8 v = *(const s16x8*)(tr + rr * 136 + ktl * 32 + (cl >> 4) * 8);
    *(s16x8*)(hb + ((size_t)ktl * 16 + f) * 512 + cl * 8) = v;
  }
}

// ---------------- gemm2: round-6 proven version (pure gload16, triple buffer) -----
__global__ __launch_bounds__(512, 4) void gemm2_kernel(
    const short* __restrict__ hfrag, const short* __restrict__ wdb,
    const int* __restrict__ cnt, const int* __restrict__ poffs,
    __hip_bfloat16* __restrict__ pout) {
  const int P = blockIdx.x;
  const int xcd = P & 7, r = P >> 3;
  const int nt = r & 15, emq = r >> 4;
  const int gm = emq * 8 + xcd;              // m-tile pinned to xcd
  const int e = gm >> 5, mt = gm & 31;
  if (mt * 256 >= cnt[e]) return;
  const int gmt = (poffs[e] >> 8) + mt;
  const int n0 = nt * 128;
  const int tid = threadIdx.x;
  const int w = tid >> 6, lane = tid & 63;
  const int wm = w >> 1, wn = w & 1;

  // per buffer (12288 shorts = 24KB): A 16 frags [0,8192), B 8 frags [8192,12288)
  __shared__ __align__(16) short Lds[3 * 12288];
  const uint32_t ldsbase = (uint32_t)(uintptr_t)&Lds[0];

  const short* srcA = hfrag + (size_t)gmt * 176 * 16 * 512 + tid * 8;
  const short* srcB = wdb + (((size_t)e * 176) * 128 + nt * 8) * 512 + tid * 8;

  const uint32_t roA = wm * 4096 + lane * 16;
  const uint32_t roB = 16384 + wn * 4096 + lane * 16;

  f32x4 acc[4][4];
#pragma unroll
  for (int i = 0; i < 4; i++)
#pragma unroll
    for (int j = 0; j < 4; j++) acc[i][j] = f32x4{0.f, 0.f, 0.f, 0.f};

#define STG2(WB) do {                                                           \
    short* d = (short*)Lds + ((WB) >> 1);                                       \
    gload16(srcA,        d + w * 512);                                          \
    gload16(srcA + 4096, d + 4096 + w * 512);                                   \
    gload16(srcB,        d + 8192 + w * 512);                                   \
    srcA += 8192; srcB += 65536; } while (0)

#define MMQ2(NF, BF)                                                            \
  { __builtin_amdgcn_s_setprio(1);                                              \
    acc[0][NF] = MFMA_BF16(af0, BF, acc[0][NF], 0, 0, 0);                       \
    acc[1][NF] = MFMA_BF16(af1, BF, acc[1][NF], 0, 0, 0);                       \
    acc[2][NF] = MFMA_BF16(af2, BF, acc[2][NF], 0, 0, 0);                       \
    acc[3][NF] = MFMA_BF16(af3, BF, acc[3][NF], 0, 0, 0);                       \
    __builtin_amdgcn_s_setprio(0); }

#define G2_BODY(RB, WB, VMN, DOSTG)                                             \
  {                                                                             \
    WAITVM(VMN);                                                                \
    __builtin_amdgcn_s_barrier();                                               \
    const uint32_t rb = ldsbase + (RB);                                         \
    s16x8 af0, af1, af2, af3, bf0, bf1, bf2, bf3;                               \
    DSR128(bf0, rb + roB, "0");                                                 \
    DSR128(af0, rb + roA, "0");    DSR128(af1, rb + roA, "1024");               \
    DSR128(af2, rb + roA, "2048"); DSR128(af3, rb + roA, "3072");               \
    DSR128(bf1, rb + roB, "1024");                                              \
    DSR128(bf2, rb + roB, "2048");                                              \
    DSR128(bf3, rb + roB, "3072");                                              \
    if (DOSTG) { STG2(WB); }                                                    \
    WAITLGKM(3);                                                                \
    MMQ2(0, bf0)                                                                \
    WAITLGKM(2);                                                                \
    MMQ2(1, bf1)                                                                \
    WAITLGKM(1);                                                                \
    MMQ2(2, bf2)                                                                \
    WAITLGKM(0);                                                                \
    MMQ2(3, bf3)                                                                \
  }

  STG2(0);
  STG2(24576);
  for (int it = 0; it < 58; ++it) {          // t = 0..173
    G2_BODY(0,     49152, 3, 1)
    G2_BODY(24576, 0,     3, 1)
    G2_BODY(49152, 24576, 3, 1)
  }
  G2_BODY(0,     0, 3, 0)                    // t=174
  G2_BODY(24576, 0, 0, 0)                    // t=175
#undef G2_BODY
#undef MMQ2
#undef STG2

  const int slotb = poffs[e] + mt * 256;
#pragma unroll
  for (int mf = 0; mf < 4; mf++) {
#pragma unroll
    for (int reg = 0; reg < 4; reg++) {
      const int row = wm * 64 + mf * 16 + (lane >> 4) * 4 + reg;
      __hip_bfloat16* op = pout + (size_t)(slotb + row) * HID + n0 + wn * 64 + (lane & 15);
#pragma unroll
      for (int nf = 0; nf < 4; nf++)
        op[nf * 16] = __float2bfloat16(acc[mf][nf][reg]);
    }
  }
}

// ---------------- combine ----------------
__global__ __launch_bounds__(256, 8) void combine_kernel(
    const __hip_bfloat16* __restrict__ pout, const int* __restrict__ tok2slot,
    const float* __restrict__ w2, float* __restrict__ out) {
  const int t = blockIdx.x;
  const int s0 = tok2slot[2 * t], s1 = tok2slot[2 * t + 1];
  const float w0 = w2[2 * t], w1 = w2[2 * t + 1];
  const short* p0 = (const short*)pout + (size_t)s0 * HID;
  const short* p1 = (const short*)pout + (size_t)s1 * HID;
  float* o = out + (size_t)t * HID;
  const int i = threadIdx.x;
  s16x8 a = *(const s16x8*)(p0 + i * 8);
  s16x8 b = *(const s16x8*)(p1 + i * 8);
  float4 r0, r1;
  r0.x = w0 * b2f(a[0]) + w1 * b2f(b[0]);
  r0.y = w0 * b2f(a[1]) + w1 * b2f(b[1]);
  r0.z = w0 * b2f(a[2]) + w1 * b2f(b[2]);
  r0.w = w0 * b2f(a[3]) + w1 * b2f(b[3]);
  r1.x = w0 * b2f(a[4]) + w1 * b2f(b[4]);
  r1.y = w0 * b2f(a[5]) + w1 * b2f(b[5]);
  r1.z = w0 * b2f(a[6]) + w1 * b2f(b[6]);
  r1.w = w0 * b2f(a[7]) + w1 * b2f(b[7]);
  *(float4*)(o + i * 8) = r0;
  *(float4*)(o + i * 8 + 4) = r1;
}

extern "C" void kernel_launch(void* const* d_in, const int* in_sizes, int n_in,
                              void* d_out, int out_size, void* d_ws, size_t ws_size,
                              hipStream_t stream) {
  const float* x  = (const float*)d_in[0];
  const float* wr = (const float*)d_in[1];
  const float* wg = (const float*)d_in[2];
  const float* wu = (const float*)d_in[3];
  const float* wd = (const float*)d_in[4];
  float* out = (float*)d_out;
  char* ws = (char*)d_ws;

  int* cnt      = (int*)ws;
  int* poffs    = (int*)(ws + 64);
  int* tcnt     = (int*)(ws + TCNT_OFF);
  int* slotlist = (int*)(ws + SLOT_OFF);
  int* tok2slot = (int*)(ws + T2S_OFF);
  float* w2     = (float*)(ws + W2_OFF);
  int* lists    = (int*)(ws + LISTS_OFF);
  float* wlists = (float*)(ws + WL_OFF);
  short* wgb    = (short*)(ws + WG_OFF);
  short* wub    = (short*)(ws + WU_OFF);
  short* wdb    = (short*)(ws + WG_OFF);     // reuses wgb region (after gemm1)
  short* hfrag  = (short*)(ws + HF_OFF);
  short* xg     = (short*)(ws + XG_OFF);
  __hip_bfloat16* pout = (__hip_bfloat16*)(ws + XG_OFF);  // reuses xg (after gemm1)

  hipMemsetAsync(ws, 0, 256, stream);
  hipMemsetAsync(ws + TCNT_OFF, 0, 32768, stream);
  hipMemsetAsync(ws + SLOT_OFF, 0, 73728, stream);

  router_kernel<<<NTOK / 4, 256, 0, stream>>>(x, wr, cnt, lists, wlists);
  offsets_kernel<<<1, 64, 0, stream>>>(cnt, poffs);
  slotmap_kernel<<<NEXP, 256, 0, stream>>>(cnt, poffs, lists, wlists, slotlist, tcnt, tok2slot, w2);
  gather_kernel<<<18432, 256, 0, stream>>>(x, slotlist, xg);
  prep_kernel<<<NEXP * 64 * 44, 256, 0, stream>>>(wg, wgb, 64, 44, INTR);
  prep_kernel<<<NEXP * 64 * 44, 256, 0, stream>>>(wu, wub, 64, 44, INTR);
  gemm1_kernel<<<8 * 32 * NT1, 512, 0, stream>>>(xg, wgb, wub, cnt, poffs, hfrag);
  prep_kernel<<<NEXP * 176 * 16, 256, 0, stream>>>(wd, wdb, 176, 16, HID);
  gemm2_kernel<<<8 * 16 * 32, 512, 0, stream>>>(hfrag, wdb, cnt, poffs, pout);
  combine_kernel<<<NTOK, 256, 0, stream>>>(pout, tok2slot, w2, out);
}